// Round 1
// baseline (29.036 us; speedup 1.0000x reference)
//
#include <hip/hip_runtime.h>

#define NQ 8
#define NL 4
#define BATCH 8192

// One sample per 16 lanes: lane bits g3..g0 hold state bits 7..4 (wires 0-3),
// register index k in [0,16) holds state bits 3..0 (wires 4-7).
// State: 16 complex amplitudes per lane = 32 f32 registers (statically indexed).
__global__ __launch_bounds__(256) void qsim(const float* __restrict__ x,
                                            const float* __restrict__ w,
                                            float* __restrict__ out)
{
    const int tid  = blockIdx.x * blockDim.x + threadIdx.x;
    const int grp  = tid >> 4;             // sample index
    if (grp >= BATCH) return;
    const int g    = threadIdx.x & 15;     // lane-within-group (state bits 7..4)
    const int lane = threadIdx.x & 63;
    const int base = lane & 48;            // group base within wave

    // ---- encoding: real product state, no gate application needed ----
    float ce[NQ], se[NQ];
    const float* xb = x + grp * NQ;
    #pragma unroll
    for (int i = 0; i < NQ; ++i) {
        float a = 0.5f * (xb[i] + w[i * 2]);   // theta = x[b,i] + weights[0,i,0]
        ce[i] = __cosf(a);
        se[i] = __sinf(a);
    }
    float Pg = ((g & 8) ? se[0] : ce[0]) * ((g & 4) ? se[1] : ce[1])
             * ((g & 2) ? se[2] : ce[2]) * ((g & 1) ? se[3] : ce[3]);
    float re[16], im[16];
    #pragma unroll
    for (int k = 0; k < 16; ++k) {
        float f = ((k & 8) ? se[4] : ce[4]) * ((k & 4) ? se[5] : ce[5])
                * ((k & 2) ? se[6] : ce[6]) * ((k & 1) ? se[7] : ce[7]);
        re[k] = Pg * f;
        im[k] = 0.0f;
    }

    // ---- entangling + rotation layers ----
    #pragma unroll 1
    for (int l = 0; l < NL; ++l) {
        float cy[NQ], sy[NQ], cz[NQ], sz[NQ];
        #pragma unroll
        for (int i = 0; i < NQ; ++i) {
            float ay = 0.5f * w[(l * NQ + i) * 2 + 0];
            float az = 0.5f * w[(l * NQ + i) * 2 + 1];
            cy[i] = __cosf(ay); sy[i] = __sinf(ay);
            cz[i] = __cosf(az); sz[i] = __sinf(az);
        }

        // CNOT(0,1),(1,2),(2,3): fused single lane permutation, src = g ^ (g>>1)
        {
            int src = base | ((g ^ (g >> 1)) & 15);
            #pragma unroll
            for (int k = 0; k < 16; ++k) {
                re[k] = __shfl(re[k], src, 64);
                im[k] = __shfl(im[k], src, 64);
            }
        }
        // CNOT(3,4): control = lane bit g0, target = register bit k3 (in-lane swap)
        {
            bool cc = (g & 1);
            #pragma unroll
            for (int k = 0; k < 8; ++k) {
                float a0 = re[k], a1 = re[k + 8];
                re[k]     = cc ? a1 : a0;
                re[k + 8] = cc ? a0 : a1;
                float b0 = im[k], b1 = im[k + 8];
                im[k]     = cc ? b1 : b0;
                im[k + 8] = cc ? b0 : b1;
            }
        }
        // CNOT(4,5),(5,6),(6,7): compile-time register permutation new[k]=old[k^(k>>1)]
        {
            float tr[16], ti[16];
            #pragma unroll
            for (int k = 0; k < 16; ++k) { int sk = k ^ (k >> 1); tr[k] = re[sk]; ti[k] = im[sk]; }
            #pragma unroll
            for (int k = 0; k < 16; ++k) { re[k] = tr[k]; im[k] = ti[k]; }
        }
        // CNOT(7,0): control = register bit k0, target = lane bit g3
        #pragma unroll
        for (int k = 1; k < 16; k += 2) {
            re[k] = __shfl_xor(re[k], 8, 64);
            im[k] = __shfl_xor(im[k], 8, 64);
        }

        // RZ then RY on wires 0..3 (lane bits, mask 8>>i)
        #pragma unroll
        for (int i = 0; i < 4; ++i) {
            const int mg = 8 >> i;
            float sg = (g & mg) ? sz[i] : -sz[i];
            #pragma unroll
            for (int k = 0; k < 16; ++k) {
                float r = re[k], q = im[k];
                re[k] = r * cz[i] - q * sg;
                im[k] = q * cz[i] + r * sg;
            }
            float sr = (g & mg) ? sy[i] : -sy[i];
            #pragma unroll
            for (int k = 0; k < 16; ++k) {
                float pr = __shfl_xor(re[k], mg, 64);
                float pi = __shfl_xor(im[k], mg, 64);
                re[k] = fmaf(cy[i], re[k], sr * pr);
                im[k] = fmaf(cy[i], im[k], sr * pi);
            }
        }
        // RZ then RY on wires 4..7 (register bits, mask 8>>(i-4))
        #pragma unroll
        for (int i = 4; i < 8; ++i) {
            const int mk = 8 >> (i - 4);
            #pragma unroll
            for (int k = 0; k < 16; ++k) {
                float sg = (k & mk) ? sz[i] : -sz[i];
                float r = re[k], q = im[k];
                re[k] = r * cz[i] - q * sg;
                im[k] = q * cz[i] + r * sg;
            }
            #pragma unroll
            for (int k = 0; k < 16; ++k) {
                if (k & mk) continue;
                int k1 = k | mk;
                float ar = re[k], ai = im[k], br = re[k1], bi = im[k1];
                re[k]  = cy[i] * ar - sy[i] * br;
                im[k]  = cy[i] * ai - sy[i] * bi;
                re[k1] = sy[i] * ar + cy[i] * br;
                im[k1] = sy[i] * ai + cy[i] * bi;
            }
        }
    }

    // ---- measurement: <Z_i> = sum_s p_s * (bit_i ? -1 : +1) ----
    float mt = 0.f, m4 = 0.f, m5 = 0.f, m6 = 0.f, m7 = 0.f;
    #pragma unroll
    for (int k = 0; k < 16; ++k) {
        float pv = re[k] * re[k] + im[k] * im[k];
        mt += pv;
        m4 += (k & 8) ? -pv : pv;
        m5 += (k & 4) ? -pv : pv;
        m6 += (k & 2) ? -pv : pv;
        m7 += (k & 1) ? -pv : pv;
    }
    float m0 = (g & 8) ? -mt : mt;
    float m1 = (g & 4) ? -mt : mt;
    float m2 = (g & 2) ? -mt : mt;
    float m3 = (g & 1) ? -mt : mt;
    #pragma unroll
    for (int d = 1; d < 16; d <<= 1) {
        m0 += __shfl_xor(m0, d, 64);
        m1 += __shfl_xor(m1, d, 64);
        m2 += __shfl_xor(m2, d, 64);
        m3 += __shfl_xor(m3, d, 64);
        m4 += __shfl_xor(m4, d, 64);
        m5 += __shfl_xor(m5, d, 64);
        m6 += __shfl_xor(m6, d, 64);
        m7 += __shfl_xor(m7, d, 64);
    }
    if (g == 0) {
        float* o = out + grp * NQ;
        o[0] = m0; o[1] = m1; o[2] = m2; o[3] = m3;
        o[4] = m4; o[5] = m5; o[6] = m6; o[7] = m7;
    }
}

extern "C" void kernel_launch(void* const* d_in, const int* in_sizes, int n_in,
                              void* d_out, int out_size, void* d_ws, size_t ws_size,
                              hipStream_t stream)
{
    const float* x = (const float*)d_in[0];
    const float* w = (const float*)d_in[1];
    float* out = (float*)d_out;
    dim3 block(256);
    dim3 grid((BATCH * 16) / 256);   // 512 blocks, 16 lanes per sample
    qsim<<<grid, block, 0, stream>>>(x, w, out);
}